// Round 10
// baseline (77.985 us; speedup 1.0000x reference)
//
#include <hip/hip_runtime.h>
#include <hip/hip_fp16.h>

// NCC (local normalized cross-correlation) loss, win=9^3, SAME zero padding.
// Volume: (B=2, C=1, D=160, H=192, W=160) fp32. Output: scalar fp32 loss.
//
// v10: wave-autonomous tiles — ZERO barriers.
//  - v4-v9 post-mortem: pipe demand (LDS 63%, VALU 46%) never saturated; the
//    residual was barrier-lockstep serialization of 4-wave blocks. Minimum
//    barrier count for a 1-wave workgroup is zero: wave64 lockstep + explicit
//    s_waitcnt lgkmcnt(0) ("memory"-clobbered) gives cross-lane LDS
//    visibility with no s_barrier. Waves are fully independent pipelines.
//  - block = 64 threads = one 16x16 (x,y) tile, streaming z in ZC=8 steps.
//    4800 blocks (~18.75 waves/CU scheduled, ~11 resident by 14.3KB LDS).
//  - no prefetch: latency hidden by wave-level TLP, not intra-wave pipelining
//    (registers stay ~110: run sums 60 + working set).
//  - dataflow per step (v8's proven math, fp16 LDS staging, fp32 z/cc math):
//    P0 z-slide (re-load sub slice, L2-hot) -> P1 stage z-sums ->
//    fence -> P2 x-boxsum (full 24-wide rows, 2 rounds) -> fence ->
//    P3 y-boxsum (40 tasks, packed fp16) -> fence -> P4 cc (4 vox/lane).
//    Hazards: all same-wave, program-ordered, each crossing >=1 fence.
//  - strides: Zq/Rq rows 24 halfs (48B: 16B-aligned, banks spread over
//    8-row period), Sq rows 16 halfs; +8-half plane pads (4-bank shift).
//  - bijective XCD-chunked swizzle; deterministic two-stage reduction.

#define NX 160
#define NY 192
#define NZ 160
#define NB 2
#define SLICE (NX * NY)            // 30720
#define VOL   (SLICE * NZ)         // 4915200
#define TOTAL (VOL * NB)           // 9830400

#define TX 16
#define TY 16
#define ZC 8
#define GXT (NX / TX)              // 10
#define GYT (NY / TY)              // 12
#define GZT (NZ / ZC)              // 20
#define NBLK (GXT * GYT * GZT * NB) // 4800

#define HR 24                      // halo rows (y)
#define ZQS 24                     // Zq row stride (halfs), 48B
#define ZQQ (HR * ZQS + 8)         // 584
#define RQS 24                     // Rq row stride (halfs), 48B
#define RQQ (HR * RQS + 8)         // 584
#define SQS 16                     // Sq row stride (halfs), 32B
#define SQQ (TY * SQS + 8)         // 264
#define INV729 (1.0f / 729.0f)

__device__ __forceinline__ void lds_fence() {
    // Same-wave cross-lane LDS visibility: drain outstanding LDS ops and pin
    // compiler ordering. No s_barrier needed — one wave per workgroup.
    asm volatile("s_waitcnt lgkmcnt(0)" ::: "memory");
}

__device__ __forceinline__ float4 f4add(float4 a, float4 b) {
    return make_float4(a.x + b.x, a.y + b.y, a.z + b.z, a.w + b.w);
}
__device__ __forceinline__ float4 f4sub(float4 a, float4 b) {
    return make_float4(a.x - b.x, a.y - b.y, a.z - b.z, a.w - b.w);
}
__device__ __forceinline__ float4 f4mul(float4 a, float4 b) {
    return make_float4(a.x * b.x, a.y * b.y, a.z * b.z, a.w * b.w);
}

union U8 { uint4 u; __half2 h[4]; };   // 8 fp16 = one b128
__device__ __forceinline__ U8 ld8(const __half* p) {
    U8 r; r.u = *(const uint4*)p; return r;
}
__device__ __forceinline__ void st8(__half* p, const U8& v) {
    *(uint4*)p = v.u;
}

__global__ __launch_bounds__(64) void ncc_main(
    const float* __restrict__ J_pred,   // predict
    const float* __restrict__ I_targ,   // target
    float* __restrict__ partial)
{
    const int lane = threadIdx.x;

    // XCD-chunked swizzle: 8 XCDs x 600 consecutive logical blocks (bijective).
    const int lin = blockIdx.x;
    const int s   = (lin & 7) * (NBLK / 8) + (lin >> 3);
    const int bx  = s % GXT;
    const int r1  = s / GXT;
    const int by  = r1 % GYT;
    const int r2  = r1 / GYT;
    const int zc  = r2 % GZT;
    const int b   = r2 / GZT;

    const int x0 = bx * TX;
    const int y0 = by * TY;
    const int z0 = zc * ZC;

    __shared__ __align__(16) __half Zq[5 * ZQQ];   // 5840 B
    __shared__ __align__(16) __half Rq[5 * RQQ];   // 5840 B
    __shared__ __align__(16) __half Sq[5 * SQQ];   // 2640 B

    // ---- column ownership: 144 float4-groups (24 rows x 6), 3 rounds ----
    // round r handles group c = lane + r*64 (round 2: lanes 0..15 only)
    int  orow[3], oxg[3];
    bool exist[3], ok[3];
    const float* bI[3];
    const float* bJ[3];
    const size_t bvol = (size_t)b * VOL;
#pragma unroll
    for (int r = 0; r < 3; ++r) {
        const int c = lane + r * 64;
        exist[r] = (c < 144);
        const int row = c / 6;
        const int x   = c - row * 6;
        orow[r] = row; oxg[r] = x;
        const int gy = y0 - 4 + row;
        const int gx = x0 - 4 + x * 4;     // 4-aligned; fully valid or fully OOB
        ok[r] = exist[r] && ((unsigned)gy < (unsigned)NY) && (gx >= 0) && (gx <= NX - 4);
        const size_t cb = bvol + (ok[r] ? (size_t)(gy * NX + gx) : 0);
        bI[r] = I_targ + cb;
        bJ[r] = J_pred + cb;
    }

    // ---- running z-box-sums (fp32, exact sliding): 3 rounds x 5 q ----
    const float4 f40 = make_float4(0.f, 0.f, 0.f, 0.f);
    float4 run[3][5];
#pragma unroll
    for (int r = 0; r < 3; ++r)
#pragma unroll
        for (int q = 0; q < 5; ++q) run[r][q] = f40;

    // warmup: add slices z0-5 .. z0+3 (OOB z -> zeros). Main loop always
    // subtracts z0+so-5; at so=0 that removes the z0-5 slice added here
    // (cancellation exact: absmax 0.0 in v2-v9 with this scheme).
#pragma unroll 1
    for (int ss = 0; ss < 9; ++ss) {
        const int z = z0 - 5 + ss;
        const bool zok = ((unsigned)z < (unsigned)NZ);
#pragma unroll
        for (int r = 0; r < 3; ++r) {
            float4 aI = f40, aJ = f40;
            if (ok[r] && zok) {
                aI = *(const float4*)(bI[r] + (size_t)z * SLICE);
                aJ = *(const float4*)(bJ[r] + (size_t)z * SLICE);
            }
            run[r][0] = f4add(run[r][0], aI);
            run[r][1] = f4add(run[r][1], aJ);
            run[r][2] = f4add(run[r][2], f4mul(aI, aI));
            run[r][3] = f4add(run[r][3], f4mul(aJ, aJ));
            run[r][4] = f4add(run[r][4], f4mul(aI, aJ));
        }
    }

    const int prow = lane >> 2;          // P4: output row (0..15)
    const int pxq  = (lane & 3) * 4;     // P4: x quad (4 voxels)
    float acc = 0.f;

#pragma unroll 1
    for (int so = 0; so < ZC; ++so) {
        // ---- P0: slide z-window (load add z0+so+4, sub z0+so-5; L2-hot) ----
        const int za = z0 + 4 + so;
        const int zs = z0 + so - 5;
        const bool zaok = ((unsigned)za < (unsigned)NZ);
        const bool zsok = (zs >= 0);
#pragma unroll
        for (int r = 0; r < 3; ++r) {
            float4 aI = f40, aJ = f40, sI = f40, sJ = f40;
            if (ok[r]) {
                if (zaok) {
                    aI = *(const float4*)(bI[r] + (size_t)za * SLICE);
                    aJ = *(const float4*)(bJ[r] + (size_t)za * SLICE);
                }
                if (zsok) {
                    sI = *(const float4*)(bI[r] + (size_t)zs * SLICE);
                    sJ = *(const float4*)(bJ[r] + (size_t)zs * SLICE);
                }
            }
            run[r][0] = f4add(run[r][0], f4sub(aI, sI));
            run[r][1] = f4add(run[r][1], f4sub(aJ, sJ));
            run[r][2] = f4add(run[r][2], f4sub(f4mul(aI, aI), f4mul(sI, sI)));
            run[r][3] = f4add(run[r][3], f4sub(f4mul(aJ, aJ), f4mul(sJ, sJ)));
            run[r][4] = f4add(run[r][4], f4sub(f4mul(aI, aJ), f4mul(sI, sJ)));
        }

        // ---- P1: stage z-sums as fp16 (b64 per q; zeros for invalid cols) ----
#pragma unroll
        for (int r = 0; r < 3; ++r) {
            if (exist[r]) {
                const int o = orow[r] * ZQS + oxg[r] * 4;
                union { uint2 u; __half2 h[2]; } pk;
#pragma unroll
                for (int q = 0; q < 5; ++q) {
                    pk.h[0] = __float22half2_rn(make_float2(run[r][q].x, run[r][q].y));
                    pk.h[1] = __float22half2_rn(make_float2(run[r][q].z, run[r][q].w));
                    *(uint2*)&Zq[q * ZQQ + o] = pk.u;
                }
            }
        }
        lds_fence();

        // ---- P2: x-boxsum, 120 full-row tasks (24 rows x 5 q), 2 rounds ----
#pragma unroll
        for (int rr = 0; rr < 2; ++rr) {
            const int t = lane + rr * 64;
            if (t < 120) {
                const int q   = t / 24;
                const int row = t - q * 24;
                const __half* src = &Zq[q * ZQQ + row * ZQS];
                float c[24];
#pragma unroll
                for (int g = 0; g < 3; ++g) {
                    U8 v = ld8(src + g * 8);
#pragma unroll
                    for (int j = 0; j < 4; ++j) {
                        const float2 f = __half22float2(v.h[j]);
                        c[g * 8 + j * 2 + 0] = f.x;
                        c[g * 8 + j * 2 + 1] = f.y;
                    }
                }
                float sx = c[0] + c[1] + c[2] + c[3] + c[4]
                         + c[5] + c[6] + c[7] + c[8];
                float o[16];
                o[0] = sx;
#pragma unroll
                for (int i = 1; i < 16; ++i) { sx += c[i + 8] - c[i - 1]; o[i] = sx; }
                __half* dst = &Rq[q * RQQ + row * RQS];
#pragma unroll
                for (int g = 0; g < 2; ++g) {
                    U8 w;
#pragma unroll
                    for (int j = 0; j < 4; ++j)
                        w.h[j] = __float22half2_rn(make_float2(o[g * 8 + j * 2],
                                                               o[g * 8 + j * 2 + 1]));
                    st8(dst + g * 8, w);
                }
            }
        }
        lds_fence();

        // ---- P3: y-boxsum, 40 tasks = 5 q x 2 xg(8 wide) x 4 row-quarters ----
        if (lane < 40) {
            const int q  = lane / 8;
            const int rm = lane - q * 8;
            const int xg = rm >> 2;    // 0..1
            const int q4 = rm & 3;     // 0..3
            const __half* rb = &Rq[q * RQQ + (q4 * 4) * RQS + xg * 8];
            __half* sb = &Sq[q * SQQ + (q4 * 4) * SQS + xg * 8];
            U8 sum = ld8(rb);
#pragma unroll
            for (int k = 1; k < 9; ++k) {
                const U8 t = ld8(rb + k * RQS);
#pragma unroll
                for (int j = 0; j < 4; ++j) sum.h[j] = __hadd2(sum.h[j], t.h[j]);
            }
            st8(sb, sum);
#pragma unroll
            for (int i = 1; i < 4; ++i) {
                const U8 nw = ld8(rb + (i + 8) * RQS);
                const U8 od = ld8(rb + (i - 1) * RQS);
#pragma unroll
                for (int j = 0; j < 4; ++j)
                    sum.h[j] = __hadd2(sum.h[j], __hsub2(nw.h[j], od.h[j]));
                st8(sb + i * SQS, sum);
            }
        }
        lds_fence();

        // ---- P4: cc for 4 voxels/lane (b64 reads, fp32 math) ----
        {
            const int o = prow * SQS + pxq;
            union { uint2 u; __half2 h[2]; } v[5];
#pragma unroll
            for (int q = 0; q < 5; ++q) v[q].u = *(const uint2*)&Sq[q * SQQ + o];
#pragma unroll
            for (int j = 0; j < 2; ++j) {
                const float2 S0 = __half22float2(v[0].h[j]);
                const float2 S1 = __half22float2(v[1].h[j]);
                const float2 S2 = __half22float2(v[2].h[j]);
                const float2 S3 = __half22float2(v[3].h[j]);
                const float2 S4 = __half22float2(v[4].h[j]);
                {
                    const float cross = S4.x - S0.x * S1.x * INV729;
                    const float Iv    = S2.x - S0.x * S0.x * INV729;
                    const float Jv    = S3.x - S1.x * S1.x * INV729;
                    acc += (cross * cross) / (Iv * Jv + 1e-5f);
                }
                {
                    const float cross = S4.y - S0.y * S1.y * INV729;
                    const float Iv    = S2.y - S0.y * S0.y * INV729;
                    const float Jv    = S3.y - S1.y * S1.y * INV729;
                    acc += (cross * cross) / (Iv * Jv + 1e-5f);
                }
            }
        }
        // P4's Sq reads drain at next step's fence after P1, before P3(t+1)
        // rewrites Sq. Zq: P2 reads drained at fence after P2, before P1(t+1).
    }

    // ---- wave reduction (deterministic) ----
#pragma unroll
    for (int off = 32; off > 0; off >>= 1) acc += __shfl_down(acc, off);
    if (lane == 0) partial[s] = acc;
}

__global__ __launch_bounds__(256) void ncc_final(
    const float* __restrict__ partial, float* __restrict__ out)
{
    __shared__ float sm[256];
    const int tid = threadIdx.x;
    float v = 0.f;
    for (int i = tid; i < NBLK; i += 256) v += partial[i];
    sm[tid] = v;
    __syncthreads();
#pragma unroll
    for (int w = 128; w > 0; w >>= 1) {
        if (tid < w) sm[tid] += sm[tid + w];
        __syncthreads();
    }
    if (tid == 0) out[0] = 1.0f - sm[0] * (1.0f / (float)TOTAL);
}

extern "C" void kernel_launch(void* const* d_in, const int* in_sizes, int n_in,
                              void* d_out, int out_size, void* d_ws, size_t ws_size,
                              hipStream_t stream)
{
    const float* predict = (const float*)d_in[0];  // J
    const float* target  = (const float*)d_in[1];  // I
    float* partial = (float*)d_ws;                 // 4800 floats (19.2 KB)

    ncc_main<<<dim3(NBLK), 64, 0, stream>>>(predict, target, partial);
    ncc_final<<<1, 256, 0, stream>>>(partial, (float*)d_out);
}

// Round 11
// 60.520 us; speedup vs baseline: 1.2886x; 1.2886x over previous
//
#include <hip/hip_runtime.h>
#include <hip/hip_fp16.h>

// NCC (local normalized cross-correlation) loss, win=9^3, SAME zero padding.
// Volume: (B=2, C=1, D=160, H=192, W=160) fp32. Output: scalar fp32 loss.
//
// v11: y-boxsum + cc moved to the (idle) MFMA pipe.
//  - y-boxsum is a banded matmul: S[y][x] = sum_k W[y][k] R[k][x], W 16x24
//    0/1 band (k-y in [0,8]) -> one mfma_f32_16x16x32_bf16 per (q, x-half):
//    10 MFMAs/step replace P3 (384 LDS-cyc) + P4 (140) + the Sq buffer.
//  - P2 writes bf16 x-sums in the ds_read_b64_tr_b16 tile layout:
//    elem(k,n) = n + 16*(k&3) + 64*(k>>3) + 256*((k>>2)&1); rows 24..31
//    zeroed once (K=32 pad). tr read: per-lane addr 2*(l&15)+128*(l>>4),
//    second read +512B; lgkmcnt(0)+sched_barrier(0) before MFMA (rule #18).
//  - waves 0/1 own x-half 0/1 (cc needs all 5 q in one lane; D gives
//    4 y-rows x 1 x per lane per half). Waves 2/3 idle in that phase only.
//  - barriers 4 -> 2 per step; sub-slice global loads issue before the MFMA
//    block (T14: ~200cyc L2 latency hides under tr+MFMA+cc).
//  - LDS 22.5 KB (Zq fp16 stride 48 + RqT bf16 10x544); lgkm-only barriers;
//    ZC=8, 2400 blocks, XCD swizzle; deterministic two-stage reduction.

#define NX 160
#define NY 192
#define NZ 160
#define NB 2
#define SLICE (NX * NY)            // 30720
#define VOL   (SLICE * NZ)         // 4915200
#define TOTAL (VOL * NB)           // 9830400

#define TX 32
#define TY 16
#define ZC 8
#define GXT (NX / TX)              // 5
#define GYT (NY / TY)              // 12
#define GZT (NZ / ZC)              // 20
#define NBLK (GXT * GYT * GZT * NB) // 2400

#define HR 24                      // y halo rows
#define ZQS 48                     // Zq row stride (halfs), 96B, 16B-aligned
#define ZQQ (HR * ZQS + 8)         // 1160
#define RGN 544                    // RqT region elems (512 data + 32 pad)
#define INV729 (1.0f / 729.0f)

typedef short bf16x8 __attribute__((ext_vector_type(8)));
typedef float f32x4 __attribute__((ext_vector_type(4)));

__device__ __forceinline__ void lds_barrier() {
    // LDS-visibility barrier WITHOUT vmcnt drain: prefetched global loads
    // stay in flight (hipcc's __syncthreads would emit s_waitcnt vmcnt(0)).
    asm volatile("s_waitcnt lgkmcnt(0)" ::: "memory");
    __builtin_amdgcn_s_barrier();
}

__device__ __forceinline__ unsigned cvt_pk_bf16(float lo, float hi) {
    unsigned r;
    asm("v_cvt_pk_bf16_f32 %0, %1, %2" : "=v"(r) : "v"(lo), "v"(hi));
    return r;
}

__device__ __forceinline__ uint2 tr_rd(unsigned a) {
    uint2 d;
    asm volatile("ds_read_b64_tr_b16 %0, %1" : "=v"(d) : "v"(a));
    return d;
}

__device__ __forceinline__ float4 f4add(float4 a, float4 b) {
    return make_float4(a.x + b.x, a.y + b.y, a.z + b.z, a.w + b.w);
}
__device__ __forceinline__ float4 f4sub(float4 a, float4 b) {
    return make_float4(a.x - b.x, a.y - b.y, a.z - b.z, a.w - b.w);
}
__device__ __forceinline__ float4 f4mul(float4 a, float4 b) {
    return make_float4(a.x * b.x, a.y * b.y, a.z * b.z, a.w * b.w);
}

union U8 { uint4 u; __half2 h[4]; };
__device__ __forceinline__ U8 ld8(const __half* p) {
    U8 r; r.u = *(const uint4*)p; return r;
}

__global__ __launch_bounds__(256) void ncc_main(
    const float* __restrict__ J_pred,   // predict
    const float* __restrict__ I_targ,   // target
    float* __restrict__ partial)
{
    const int tid = threadIdx.x;

    // XCD-chunked swizzle: 8 XCDs x 300 consecutive logical blocks (bijective).
    const int lin = blockIdx.x;
    const int s   = (lin & 7) * (NBLK / 8) + (lin >> 3);
    const int bx  = s % GXT;
    const int r1  = s / GXT;
    const int by  = r1 % GYT;
    const int r2  = r1 / GYT;
    const int zc  = r2 % GZT;
    const int b   = r2 / GZT;

    const int x0 = bx * TX;
    const int y0 = by * TY;
    const int z0 = zc * ZC;

    __shared__ __align__(16) __half Zq[5 * ZQQ];    // 11600 B (fp16 z-sums)
    __shared__ __align__(16) short  RqT[10 * RGN];  // 10880 B (bf16 x-sums, tr tiles)
    __shared__ float redbuf[4];

    // ---- one-time: zero K-pad rows 24..31 of every region ----
    if (tid < 160) {
        const int r = tid >> 4, slot = tid & 15;
        const int e = (slot < 8) ? (192 + slot * 8) : (448 + (slot - 8) * 8);
        *(uint4*)&RqT[r * RGN + e] = make_uint4(0, 0, 0, 0);
    }

    // ---- float4 column ownership: 240 tasks = 24 rows x 10 groups ----
    const bool is_col = (tid < 240);
    const int  crow = tid / 10;
    const int  cxg  = tid - crow * 10;
    const int  gy = y0 - 4 + crow;
    const int  gx = x0 - 4 + cxg * 4;
    const bool vxy = is_col && ((unsigned)gy < (unsigned)NY) && (gx >= 0) && (gx <= NX - 4);
    const size_t cbase = (size_t)b * VOL + (vxy ? (size_t)(gy * NX + gx) : 0);
    const float* const baseI = I_targ + cbase;
    const float* const baseJ = J_pred + cbase;

    // ---- MFMA constants: banded W fragment + tr-read base address ----
    const int lane = tid & 63;
    bf16x8 wfrag;
    {
        const int m = lane & 15, kb = (lane >> 4) * 8;
#pragma unroll
        for (int j = 0; j < 8; ++j) {
            const int k = kb + j;
            wfrag[j] = (k >= m && k <= m + 8) ? (short)0x3F80 : (short)0;
        }
    }
    const unsigned rqbase = (unsigned)(size_t)&RqT[0];
    const unsigned trlane = rqbase + 2u * (unsigned)(lane & 15) + 128u * (unsigned)(lane >> 4);

    // ---- running z-box-sums (fp32, exact sliding) ----
    const float4 f40 = make_float4(0.f, 0.f, 0.f, 0.f);
    float4 rS0 = f40, rS1 = f40, rS2 = f40, rS3 = f40, rS4 = f40;

    // warmup: add slices z0-5 .. z0+3 (OOB z -> zeros); P0 of step s always
    // subtracts z0+s-5, which at s=0 removes the z0-5 added here.
#pragma unroll 1
    for (int ss = 0; ss < 9; ++ss) {
        const int z = z0 - 5 + ss;
        float4 aI = f40, aJ = f40;
        if (vxy && (unsigned)z < (unsigned)NZ) {
            aI = *(const float4*)(baseI + (size_t)z * SLICE);
            aJ = *(const float4*)(baseJ + (size_t)z * SLICE);
        }
        rS0 = f4add(rS0, aI);
        rS1 = f4add(rS1, aJ);
        rS2 = f4add(rS2, f4mul(aI, aI));
        rS3 = f4add(rS3, f4mul(aJ, aJ));
        rS4 = f4add(rS4, f4mul(aI, aJ));
    }

    // pending add-slice for step 0 (z0+4 always < NZ)
    float4 nIa = f40, nJa = f40;
    if (vxy) {
        nIa = *(const float4*)(baseI + (size_t)(z0 + 4) * SLICE);
        nJa = *(const float4*)(baseJ + (size_t)(z0 + 4) * SLICE);
    }

    float acc = 0.f;

    // ---- phase lambdas ----
    auto do_P1 = [&]() {   // stage z-sums as fp16
        if (is_col) {
            const int o = crow * ZQS + cxg * 4;
            union { uint2 u; __half2 h[2]; } pk;
            pk.h[0] = __float22half2_rn(make_float2(rS0.x, rS0.y));
            pk.h[1] = __float22half2_rn(make_float2(rS0.z, rS0.w));
            *(uint2*)&Zq[0 * ZQQ + o] = pk.u;
            pk.h[0] = __float22half2_rn(make_float2(rS1.x, rS1.y));
            pk.h[1] = __float22half2_rn(make_float2(rS1.z, rS1.w));
            *(uint2*)&Zq[1 * ZQQ + o] = pk.u;
            pk.h[0] = __float22half2_rn(make_float2(rS2.x, rS2.y));
            pk.h[1] = __float22half2_rn(make_float2(rS2.z, rS2.w));
            *(uint2*)&Zq[2 * ZQQ + o] = pk.u;
            pk.h[0] = __float22half2_rn(make_float2(rS3.x, rS3.y));
            pk.h[1] = __float22half2_rn(make_float2(rS3.z, rS3.w));
            *(uint2*)&Zq[3 * ZQQ + o] = pk.u;
            pk.h[0] = __float22half2_rn(make_float2(rS4.x, rS4.y));
            pk.h[1] = __float22half2_rn(make_float2(rS4.z, rS4.w));
            *(uint2*)&Zq[4 * ZQQ + o] = pk.u;
        }
    };

    auto do_P2 = [&]() {   // x-boxsum: fp16 in, f32 slide, bf16 tr-tile out
        if (tid < 240) {
            const int q   = tid / 48;
            const int rem = tid - q * 48;
            const int row = rem >> 1;
            const int h   = rem & 1;
            const __half* src = &Zq[q * ZQQ + row * ZQS + h * 16];
            float c[24];
#pragma unroll
            for (int g = 0; g < 3; ++g) {
                U8 v = ld8(src + g * 8);
#pragma unroll
                for (int j = 0; j < 4; ++j) {
                    const float2 f = __half22float2(v.h[j]);
                    c[g * 8 + j * 2 + 0] = f.x;
                    c[g * 8 + j * 2 + 1] = f.y;
                }
            }
            float sx = c[0] + c[1] + c[2] + c[3] + c[4]
                     + c[5] + c[6] + c[7] + c[8];
            float o[16];
            o[0] = sx;
#pragma unroll
            for (int i = 1; i < 16; ++i) { sx += c[i + 8] - c[i - 1]; o[i] = sx; }
            unsigned u[8];
#pragma unroll
            for (int i = 0; i < 8; ++i) u[i] = cvt_pk_bf16(o[2 * i], o[2 * i + 1]);
            const int e = 16 * (row & 3) + 64 * (row >> 3) + 256 * ((row >> 2) & 1);
            short* dst = &RqT[(q * 2 + h) * RGN + e];
            *(uint4*)(dst + 0) = make_uint4(u[0], u[1], u[2], u[3]);
            *(uint4*)(dst + 8) = make_uint4(u[4], u[5], u[6], u[7]);
        }
    };

    auto do_mfmacc = [&]() {   // y-boxsum via MFMA + cc, waves 0/1 only
        if (tid < 128) {
            const int h = tid >> 6;                     // x-half
            const unsigned abase = trlane + (unsigned)h * 1088u;
            const f32x4 z4 = {0.f, 0.f, 0.f, 0.f};
            f32x4 D[5];
#pragma unroll
            for (int q = 0; q < 5; ++q) {
                const unsigned a = abase + (unsigned)q * 2176u;
                uint2 b0 = tr_rd(a);
                uint2 b1 = tr_rd(a + 512u);
                asm volatile("s_waitcnt lgkmcnt(0)" ::: "memory");
                __builtin_amdgcn_sched_barrier(0);
                union { uint2 u[2]; bf16x8 v; } bb;
                bb.u[0] = b0; bb.u[1] = b1;
                D[q] = __builtin_amdgcn_mfma_f32_16x16x32_bf16(wfrag, bb.v, z4, 0, 0, 0);
            }
#pragma unroll
            for (int r = 0; r < 4; ++r) {
                const float S0 = D[0][r], S1 = D[1][r], S2 = D[2][r],
                            S3 = D[3][r], S4 = D[4][r];
                const float cross = S4 - S0 * S1 * INV729;
                const float Iv    = S2 - S0 * S0 * INV729;
                const float Jv    = S3 - S1 * S1 * INV729;
                acc += (cross * cross) / (Iv * Jv + 1e-5f);
            }
        }
    };

    // ---- prologue: step 0 staged through its x-boxsum ----
    {
        // P0(0): add pending z0+4; sub z0-5 (<0 at zc==0 -> zeros)
        float4 sI = f40, sJ = f40;
        const int zs = z0 - 5;
        if (vxy && zs >= 0) {
            sI = *(const float4*)(baseI + (size_t)zs * SLICE);
            sJ = *(const float4*)(baseJ + (size_t)zs * SLICE);
        }
        rS0 = f4add(rS0, f4sub(nIa, sI));
        rS1 = f4add(rS1, f4sub(nJa, sJ));
        rS2 = f4add(rS2, f4sub(f4mul(nIa, nIa), f4mul(sI, sI)));
        rS3 = f4add(rS3, f4sub(f4mul(nJa, nJa), f4mul(sJ, sJ)));
        rS4 = f4add(rS4, f4sub(f4mul(nIa, nJa), f4mul(sI, sJ)));
        nIa = f40; nJa = f40;
        if (vxy) {   // prefetch add-slice for step 1 (z0+5 < NZ always)
            nIa = *(const float4*)(baseI + (size_t)(z0 + 5) * SLICE);
            nJa = *(const float4*)(baseJ + (size_t)(z0 + 5) * SLICE);
        }
        do_P1();
        lds_barrier();   // barA
        do_P2();
        lds_barrier();   // barB
    }

    // ---- 2-barrier body: stage step t+1, consume step t ----
#pragma unroll 1
    for (int t = 0; t < ZC - 1; ++t) {
        const int ss = t + 1;
        // P0a: issue sub loads early (L2 latency hides under tr+MFMA+cc)
        float4 sI = f40, sJ = f40;
        const int zs = z0 + ss - 5;
        if (vxy && zs >= 0) {
            sI = *(const float4*)(baseI + (size_t)zs * SLICE);
            sJ = *(const float4*)(baseJ + (size_t)zs * SLICE);
        }

        do_mfmacc();     // consume step t (reads RqT(t), regs only after)

        // P0b: z-window update for step ss + prefetch add for ss+1
        rS0 = f4add(rS0, f4sub(nIa, sI));
        rS1 = f4add(rS1, f4sub(nJa, sJ));
        rS2 = f4add(rS2, f4sub(f4mul(nIa, nIa), f4mul(sI, sI)));
        rS3 = f4add(rS3, f4sub(f4mul(nJa, nJa), f4mul(sJ, sJ)));
        rS4 = f4add(rS4, f4sub(f4mul(nIa, nJa), f4mul(sI, sJ)));
        nIa = f40; nJa = f40;
        if (ss < ZC - 1 && vxy) {
            const int za = z0 + 5 + ss;
            if (za < NZ) {
                nIa = *(const float4*)(baseI + (size_t)za * SLICE);
                nJa = *(const float4*)(baseJ + (size_t)za * SLICE);
            }
        }

        do_P1();         // stage Zq(ss)  [Zq readers of step t done before barB(t-1)]
        lds_barrier();   // barA: Zq(ss) ready; RqT(t) reads complete
        do_P2();         // RqT(ss)
        lds_barrier();   // barB: RqT(ss) ready
    }

    do_mfmacc();         // consume final step ZC-1

    // ---- block reduction (deterministic within block) ----
#pragma unroll
    for (int off = 32; off > 0; off >>= 1) acc += __shfl_down(acc, off);
    __syncthreads();
    if ((tid & 63) == 0) redbuf[tid >> 6] = acc;
    __syncthreads();
    if (tid == 0) partial[s] = redbuf[0] + redbuf[1] + redbuf[2] + redbuf[3];
}

__global__ __launch_bounds__(256) void ncc_final(
    const float* __restrict__ partial, float* __restrict__ out)
{
    __shared__ float sm[256];
    const int tid = threadIdx.x;
    float v = 0.f;
    for (int i = tid; i < NBLK; i += 256) v += partial[i];
    sm[tid] = v;
    __syncthreads();
#pragma unroll
    for (int w = 128; w > 0; w >>= 1) {
        if (tid < w) sm[tid] += sm[tid + w];
        __syncthreads();
    }
    if (tid == 0) out[0] = 1.0f - sm[0] * (1.0f / (float)TOTAL);
}

extern "C" void kernel_launch(void* const* d_in, const int* in_sizes, int n_in,
                              void* d_out, int out_size, void* d_ws, size_t ws_size,
                              hipStream_t stream)
{
    const float* predict = (const float*)d_in[0];  // J
    const float* target  = (const float*)d_in[1];  // I
    float* partial = (float*)d_ws;                 // 2400 floats (9.6 KB)

    ncc_main<<<dim3(NBLK), 256, 0, stream>>>(predict, target, partial);
    ncc_final<<<1, 256, 0, stream>>>(partial, (float*)d_out);
}